// Round 8
// baseline (529.583 us; speedup 1.0000x reference)
//
#include <hip/hip_runtime.h>
#include <hip/hip_bf16.h>

// ---------------------------------------------------------------------------
// EGNN layer, v8: R7 math, re-tiled edge kernel for occupancy.
//   32 CSR slots/block, 512 threads, ~21KB LDS, VGPR<=64 -> up to 32 waves/CU
//   co-resident (4 blocks) so cross-block phase overlap hides barrier stalls.
//   Coord head transposed (in-lane reduce). nmsg via segmented in-kernel
//   reduction (plain stores interior, atomics at window edges).
// ---------------------------------------------------------------------------

#define NN 16384
#define EE 262144
#define HH 256
#define RR 32

typedef __bf16 bf16x8 __attribute__((ext_vector_type(8)));
typedef float f32x4 __attribute__((ext_vector_type(4)));

__device__ __forceinline__ float silu_f(float x) { return x / (1.0f + __expf(-x)); }

__device__ __forceinline__ unsigned short bf_bits(float x) {
  union { __hip_bfloat16 b; unsigned short u; } v;
  v.b = __float2bfloat16(x);
  return v.u;
}
__device__ __forceinline__ float ubf(unsigned short u) {
  return __uint_as_float(((unsigned)u) << 16);
}

// ---------------- prep ----------------
__global__ __launch_bounds__(256) void conv_h_kernel(const float* __restrict__ src,
                                                     __hip_bfloat16* __restrict__ dst,
                                                     int n4) {
  int i = blockIdx.x * 256 + threadIdx.x;
  if (i >= n4) return;
  float4 v = ((const float4*)src)[i];
  __hip_bfloat16* d = dst + (size_t)i * 4;
  d[0] = __float2bfloat16(v.x);
  d[1] = __float2bfloat16(v.y);
  d[2] = __float2bfloat16(v.z);
  d[3] = __float2bfloat16(v.w);
}

__global__ __launch_bounds__(256) void prep_w_kernel(
    const float* __restrict__ en_w1, const float* __restrict__ en_w2,
    const float* __restrict__ nn_w1, const float* __restrict__ nn_w2,
    const float* __restrict__ cn_w1, const float* __restrict__ rb_w2,
    const float* __restrict__ rb_b2, const float* __restrict__ en_b1,
    __hip_bfloat16* __restrict__ W2T, __hip_bfloat16* __restrict__ NW1T,
    __hip_bfloat16* __restrict__ NW2T, __hip_bfloat16* __restrict__ CW1T,
    __hip_bfloat16* __restrict__ W1abT, __hip_bfloat16* __restrict__ RWT,
    float* __restrict__ b1p) {
  int bid = blockIdx.x, tid = threadIdx.x;
  if (bid < 256) {
    int i = bid * 256 + tid, k = i >> 8, c = i & 255;
    W2T[(size_t)c * 256 + k] = __float2bfloat16(en_w2[i]);
  } else if (bid < 768) {
    int i = (bid - 256) * 256 + tid, k = i >> 8, c = i & 255;
    NW1T[(size_t)c * 512 + k] = __float2bfloat16(nn_w1[i]);
  } else if (bid < 1024) {
    int i = (bid - 768) * 256 + tid, k = i >> 8, c = i & 255;
    NW2T[(size_t)c * 256 + k] = __float2bfloat16(nn_w2[i]);
  } else if (bid < 1152) {
    int i = (bid - 1024) * 256 + tid, k = i >> 7, c = i & 127;
    CW1T[(size_t)c * 256 + k] = __float2bfloat16(cn_w1[i]);
  } else if (bid < 1408) {
    int i = (bid - 1152) * 256 + tid, k = i >> 8, c = i & 255;
    W1abT[(size_t)c * 256 + k] = __float2bfloat16(en_w1[i]);
  } else if (bid < 1664) {
    int i = (bid - 1408) * 256 + tid, k = i >> 8, c = i & 255;
    W1abT[(size_t)(256 + c) * 256 + k] = __float2bfloat16(en_w1[256 * 256 + i]);
  } else if (bid < 1696) {
    int t = (bid - 1664) * 256 + tid;
    int c = t >> 5, i = t & 31;
    float s = 0.f;
#pragma unroll
    for (int j = 0; j < 32; ++j) s += rb_w2[i * 32 + j] * en_w1[(512 + j) * 256 + c];
    RWT[c * 32 + i] = __float2bfloat16(s);
  } else {
    int c = tid;
    float s = en_b1[c];
#pragma unroll
    for (int j = 0; j < 32; ++j) s += rb_b2[j] * en_w1[(512 + j) * 256 + c];
    b1p[c] = s;
  }
}

// ---------------- CSR build (col) ----------------
__global__ __launch_bounds__(256) void count_kernel(const int* __restrict__ ei,
                                                    int* __restrict__ counts) {
  int e = blockIdx.x * 256 + threadIdx.x;
  if (e >= EE) return;
  atomicAdd(&counts[ei[EE + e]], 1);
}

__global__ __launch_bounds__(256) void scanA_kernel(const int* __restrict__ counts,
                                                    int* __restrict__ bsum) {
  __shared__ int ws[4];
  int t = threadIdx.x;
  int v = counts[blockIdx.x * 256 + t];
#pragma unroll
  for (int m = 1; m < 64; m <<= 1) v += __shfl_xor(v, m, 64);
  if ((t & 63) == 0) ws[t >> 6] = v;
  __syncthreads();
  if (t == 0) bsum[blockIdx.x] = ws[0] + ws[1] + ws[2] + ws[3];
}

__global__ __launch_bounds__(64) void scanB_kernel(const int* __restrict__ bsum,
                                                   int* __restrict__ bbase,
                                                   int* __restrict__ offs) {
  int t = threadIdx.x;
  int v = bsum[t], x = v;
#pragma unroll
  for (int d = 1; d < 64; d <<= 1) {
    int y = __shfl_up(x, d, 64);
    if (t >= d) x += y;
  }
  bbase[t] = x - v;
  if (t == 63) offs[NN] = x;
}

__global__ __launch_bounds__(256) void scanC_kernel(const int* __restrict__ counts,
                                                    const int* __restrict__ bbase,
                                                    int* __restrict__ offs,
                                                    int* __restrict__ cursor) {
  __shared__ int wtot[4];
  int t = threadIdx.x, wv = t >> 6, ln = t & 63;
  int base = blockIdx.x * 256;
  int v = counts[base + t], x = v;
#pragma unroll
  for (int d = 1; d < 64; d <<= 1) {
    int y = __shfl_up(x, d, 64);
    if (ln >= d) x += y;
  }
  if (ln == 63) wtot[wv] = x;
  __syncthreads();
  int add = bbase[blockIdx.x];
  for (int k = 0; k < wv; ++k) add += wtot[k];
  int excl = add + x - v;
  offs[base + t] = excl;
  cursor[base + t] = excl;
}

__global__ __launch_bounds__(256) void scatter_kernel(const int* __restrict__ ei,
                                                      int* __restrict__ cursor,
                                                      int* __restrict__ elist) {
  int e = blockIdx.x * 256 + threadIdx.x;
  if (e >= EE) return;
  int c = ei[EE + e];
  int p = atomicAdd(&cursor[c], 1);
  elist[p] = e;
}

// ---------------- P = h @ [W1a|W1b] : [N,512] bf16 ----------------
__global__ __launch_bounds__(512) void pgemm_kernel(const __hip_bfloat16* __restrict__ A,
                                                    const __hip_bfloat16* __restrict__ BT,
                                                    __hip_bfloat16* __restrict__ out) {
  const int tid = threadIdx.x, w = tid >> 6, l = tid & 63, r = l & 15, g = l >> 4;
  const int n0 = blockIdx.x * 64;
  f32x4 acc[4][4];
#pragma unroll
  for (int a = 0; a < 4; ++a)
#pragma unroll
    for (int b = 0; b < 4; ++b) acc[a][b] = (f32x4){0.f, 0.f, 0.f, 0.f};
  for (int ks = 0; ks < 8; ++ks) {
    bf16x8 af[4], bfr[4];
#pragma unroll
    for (int fm = 0; fm < 4; ++fm)
      af[fm] = *(const bf16x8*)(A + (size_t)(n0 + fm * 16 + r) * 256 + ks * 32 + g * 8);
#pragma unroll
    for (int fn = 0; fn < 4; ++fn)
      bfr[fn] = *(const bf16x8*)(BT + (size_t)(w * 64 + fn * 16 + r) * 256 + ks * 32 + g * 8);
#pragma unroll
    for (int fm = 0; fm < 4; ++fm)
#pragma unroll
      for (int fn = 0; fn < 4; ++fn)
        acc[fm][fn] =
            __builtin_amdgcn_mfma_f32_16x16x32_bf16(af[fm], bfr[fn], acc[fm][fn], 0, 0, 0);
  }
#pragma unroll
  for (int fm = 0; fm < 4; ++fm)
#pragma unroll
    for (int fn = 0; fn < 4; ++fn) {
      int col = w * 64 + fn * 16 + r;
#pragma unroll
      for (int q = 0; q < 4; ++q) {
        int row = n0 + fm * 16 + g * 4 + q;
        out[(size_t)row * 512 + col] = __float2bfloat16(acc[fm][fn][q]);
      }
    }
}

// ---------------- fused edge kernel: 32 CSR slots/block, 512 threads ----------------
__global__ __launch_bounds__(512, 8) void edge_kernel(
    const __hip_bfloat16* __restrict__ Pb, const int* __restrict__ ei,
    const float* __restrict__ pos, const float* __restrict__ rb_w1,
    const float* __restrict__ rb_b1, const __hip_bfloat16* __restrict__ RWT,
    const float* __restrict__ b1p, const __hip_bfloat16* __restrict__ W2T,
    const float* __restrict__ en_b2, const float* __restrict__ en_g,
    const float* __restrict__ en_bt, const __hip_bfloat16* __restrict__ CW1T,
    const float* __restrict__ cn_b1, const float* __restrict__ cn_w2,
    const float* __restrict__ cn_b2, const int* __restrict__ elist,
    float* __restrict__ nmsg, float* __restrict__ pos_out) {
  __shared__ __align__(16) __hip_bfloat16 A2[32 * 264];  // rad -> hidden -> msg
  __shared__ float relb[32][3];
  __shared__ float distb[32];
  __shared__ int srow[32], scol[32];
  __shared__ float red[8][32], redsq[8][32];
  __shared__ float mv[32][2];
  __shared__ float cb1b[128], cw2b[128];

  const int tid = threadIdx.x, w = tid >> 6, l = tid & 63, r = l & 15, g = l >> 4;
  const int e0 = blockIdx.x * 32;

  if (tid < 128) {
    cb1b[tid] = cn_b1[tid];
    cw2b[tid] = cn_w2[tid];
  }
  if (tid < 32) {
    int e = elist[e0 + tid];
    int r2 = ei[e], c2 = ei[EE + e];
    srow[tid] = r2;
    scol[tid] = c2;
    float dx = pos[c2 * 3 + 0] - pos[r2 * 3 + 0];
    float dy = pos[c2 * 3 + 1] - pos[r2 * 3 + 1];
    float dz = pos[c2 * 3 + 2] - pos[r2 * 3 + 2];
    relb[tid][0] = dx;
    relb[tid][1] = dy;
    relb[tid][2] = dz;
    float ex = dx + 1e-8f, ey = dy + 1e-8f, ez = dz + 1e-8f;
    distb[tid] = sqrtf(ex * ex + ey * ey + ez * ez);
  }
  __syncthreads();  // #1: meta ready

  // ---- rad pre-pass (transposed MFMA) ----
  unsigned short* A2u = (unsigned short*)A2;
  {
    const int eloc = (w & 1) * 16 + r;
    const int chalf = w >> 1;  // 0..3
    float d = distb[eloc];
    bf16x8 sfrag;
#pragma unroll
    for (int j = 0; j < 8; ++j) {
      float x = d * rb_w1[g * 8 + j] + rb_b1[g * 8 + j];
      sfrag[j] = (__bf16)silu_f(x);
    }
#pragma unroll
    for (int t = 0; t < 4; ++t) {
      int cblk = chalf * 4 + t;
      int cbase = cblk * 16 + g * 4;
      bf16x8 afr = *(const bf16x8*)(RWT + (size_t)(cblk * 16 + r) * 32 + g * 8);
      f32x4 rad = __builtin_amdgcn_mfma_f32_16x16x32_bf16(
          afr, sfrag, (f32x4){0.f, 0.f, 0.f, 0.f}, 0, 0, 0);
      ushort4 o;
      o.x = bf_bits(rad[0]);
      o.y = bf_bits(rad[1]);
      o.z = bf_bits(rad[2]);
      o.w = bf_bits(rad[3]);
      *(ushort4*)(A2u + (size_t)eloc * 264 + cbase) = o;
    }
  }
  __syncthreads();  // #2: rad in A2

  // ---- staging: hidden = silu(rad + P1 + P2 + b1p), coalesced 16B gathers ----
#pragma unroll
  for (int it = 0; it < 2; ++it) {
    int ch = it * 512 + tid;  // 1024 chunks of 8 elems
    int i = ch >> 5, c = ch & 31;
    bf16x8 radv = *(const bf16x8*)(A2 + i * 264 + c * 8);
    bf16x8 p1 = *(const bf16x8*)(Pb + (size_t)srow[i] * 512 + c * 8);
    bf16x8 p2 = *(const bf16x8*)(Pb + (size_t)scol[i] * 512 + 256 + c * 8);
    float4 b1a = *(const float4*)(b1p + c * 8);
    float4 b1b = *(const float4*)(b1p + c * 8 + 4);
    float bv[8] = {b1a.x, b1a.y, b1a.z, b1a.w, b1b.x, b1b.y, b1b.z, b1b.w};
    bf16x8 o;
#pragma unroll
    for (int j = 0; j < 8; ++j)
      o[j] = (__bf16)silu_f((float)radv[j] + (float)p1[j] + (float)p2[j] + bv[j]);
    *(bf16x8*)(A2 + i * 264 + c * 8) = o;
  }
  __syncthreads();  // #3: hidden ready

  // ---- GEMM2 (transposed): D[c'][e], A=W2T rows (c'=w*32+mf*16+g*4+q), e=nf*16+r ----
  f32x4 acc[2][2];
#pragma unroll
  for (int a = 0; a < 2; ++a)
#pragma unroll
    for (int b = 0; b < 2; ++b) acc[a][b] = (f32x4){0.f, 0.f, 0.f, 0.f};
  for (int ks = 0; ks < 8; ++ks) {
    bf16x8 af[2], bfr[2];
#pragma unroll
    for (int mf = 0; mf < 2; ++mf)
      af[mf] = *(const bf16x8*)(W2T + (size_t)(w * 32 + mf * 16 + r) * 256 + ks * 32 + g * 8);
#pragma unroll
    for (int nf = 0; nf < 2; ++nf)
      bfr[nf] = *(const bf16x8*)(A2 + (nf * 16 + r) * 264 + ks * 32 + g * 8);
#pragma unroll
    for (int mf = 0; mf < 2; ++mf)
#pragma unroll
      for (int nf = 0; nf < 2; ++nf)
        acc[mf][nf] =
            __builtin_amdgcn_mfma_f32_16x16x32_bf16(af[mf], bfr[nf], acc[mf][nf], 0, 0, 0);
  }
  {
    float4 b2v0 = *(const float4*)(en_b2 + w * 32 + g * 4);
    float4 b2v1 = *(const float4*)(en_b2 + w * 32 + 16 + g * 4);
#pragma unroll
    for (int nf = 0; nf < 2; ++nf) {
      acc[0][nf][0] += b2v0.x;
      acc[0][nf][1] += b2v0.y;
      acc[0][nf][2] += b2v0.z;
      acc[0][nf][3] += b2v0.w;
      acc[1][nf][0] += b2v1.x;
      acc[1][nf][1] += b2v1.y;
      acc[1][nf][2] += b2v1.z;
      acc[1][nf][3] += b2v1.w;
    }
  }

  // ---- LN stats ----
#pragma unroll
  for (int nf = 0; nf < 2; ++nf) {
    float s = 0.f, sq = 0.f;
#pragma unroll
    for (int mf = 0; mf < 2; ++mf)
#pragma unroll
      for (int q = 0; q < 4; ++q) {
        float v = acc[mf][nf][q];
        s += v;
        sq += v * v;
      }
    s += __shfl_xor(s, 16, 64);
    s += __shfl_xor(s, 32, 64);
    sq += __shfl_xor(sq, 16, 64);
    sq += __shfl_xor(sq, 32, 64);
    if (l < 16) {
      red[w][nf * 16 + l] = s;
      redsq[w][nf * 16 + l] = sq;
    }
  }
  __syncthreads();  // #4
  if (tid < 32) {
    float s = 0.f, sq = 0.f;
#pragma unroll
    for (int k = 0; k < 8; ++k) {
      s += red[k][tid];
      sq += redsq[k][tid];
    }
    float mean = s * (1.0f / HH);
    float var = sq * (1.0f / HH) - mean * mean;
    mv[tid][0] = mean;
    mv[tid][1] = rsqrtf(var + 1e-5f);
  }
  __syncthreads();  // #5

  // ---- LN apply: packed ushort4 writes into A2 ----
  {
    float4 gv0 = *(const float4*)(en_g + w * 32 + g * 4);
    float4 gv1 = *(const float4*)(en_g + w * 32 + 16 + g * 4);
    float4 bv0 = *(const float4*)(en_bt + w * 32 + g * 4);
    float4 bv1 = *(const float4*)(en_bt + w * 32 + 16 + g * 4);
#pragma unroll
    for (int nf = 0; nf < 2; ++nf) {
      int e = nf * 16 + r;
      float mm = mv[e][0], rs = mv[e][1];
      ushort4 o0, o1;
      o0.x = bf_bits((acc[0][nf][0] - mm) * rs * gv0.x + bv0.x);
      o0.y = bf_bits((acc[0][nf][1] - mm) * rs * gv0.y + bv0.y);
      o0.z = bf_bits((acc[0][nf][2] - mm) * rs * gv0.z + bv0.z);
      o0.w = bf_bits((acc[0][nf][3] - mm) * rs * gv0.w + bv0.w);
      o1.x = bf_bits((acc[1][nf][0] - mm) * rs * gv1.x + bv1.x);
      o1.y = bf_bits((acc[1][nf][1] - mm) * rs * gv1.y + bv1.y);
      o1.z = bf_bits((acc[1][nf][2] - mm) * rs * gv1.z + bv1.z);
      o1.w = bf_bits((acc[1][nf][3] - mm) * rs * gv1.w + bv1.w);
      *(ushort4*)(A2u + (size_t)e * 264 + w * 32 + g * 4) = o0;
      *(ushort4*)(A2u + (size_t)e * 264 + w * 32 + 16 + g * 4) = o1;
    }
  }
  __syncthreads();  // #6: msg ready in A2

  // ---- coord head (transposed): c' = w*16+g*4+q, e = nf*16+r ----
  {
    f32x4 cacc[2];
    cacc[0] = (f32x4){0.f, 0.f, 0.f, 0.f};
    cacc[1] = (f32x4){0.f, 0.f, 0.f, 0.f};
    for (int ks = 0; ks < 8; ++ks) {
      bf16x8 af2 = *(const bf16x8*)(CW1T + (size_t)(w * 16 + r) * 256 + ks * 32 + g * 8);
      bf16x8 bfr[2];
#pragma unroll
      for (int nf = 0; nf < 2; ++nf)
        bfr[nf] = *(const bf16x8*)(A2 + (nf * 16 + r) * 264 + ks * 32 + g * 8);
#pragma unroll
      for (int nf = 0; nf < 2; ++nf)
        cacc[nf] = __builtin_amdgcn_mfma_f32_16x16x32_bf16(af2, bfr[nf], cacc[nf], 0, 0, 0);
    }
    float4 cb = *(const float4*)(cb1b + w * 16 + g * 4);
    float4 cw = *(const float4*)(cw2b + w * 16 + g * 4);
#pragma unroll
    for (int nf = 0; nf < 2; ++nf) {
      float v = silu_f(cacc[nf][0] + cb.x) * cw.x + silu_f(cacc[nf][1] + cb.y) * cw.y +
                silu_f(cacc[nf][2] + cb.z) * cw.z + silu_f(cacc[nf][3] + cb.w) * cw.w;
      v += __shfl_xor(v, 16, 64);
      v += __shfl_xor(v, 32, 64);
      if (l < 16) red[w][nf * 16 + l] = v;
    }
  }

  // ---- segmented nmsg reduction (lane-contiguous; plain stores interior) ----
  {
    int c = tid & 255, h = tid >> 8;
    int rbeg = h * 16, rend = rbeg + 16;
    int segstart = rbeg;
    int cur = scol[rbeg];
    float run = 0.f;
    for (int row = rbeg; row < rend; ++row) {
      int nd = scol[row];
      if (nd != cur) {
        float* dst = &nmsg[(size_t)cur * 256 + c];
        if (segstart > rbeg)
          *dst = run;  // interior segment: exclusive by CSR contiguity
        else
          atomicAdd(dst, run);
        segstart = row;
        cur = nd;
        run = 0.f;
      }
      run += ubf(A2u[(size_t)row * 264 + c]);
    }
    atomicAdd(&nmsg[(size_t)cur * 256 + c], run);
  }
  __syncthreads();  // #7
  if (tid < 32) {
    float s = cn_b2[0];
#pragma unroll
    for (int k = 0; k < 8; ++k) s += red[k][tid];
    float wgt = tanhf(s);
    float ax = relb[tid][0], ay = relb[tid][1], az = relb[tid][2];
    int rr = srow[tid], cc = scol[tid];
    atomicAdd(&pos_out[rr * 3 + 0], -wgt * ax);
    atomicAdd(&pos_out[rr * 3 + 1], -wgt * ay);
    atomicAdd(&pos_out[rr * 3 + 2], -wgt * az);
    atomicAdd(&pos_out[cc * 3 + 0], wgt * ax);
    atomicAdd(&pos_out[cc * 3 + 1], wgt * ay);
    atomicAdd(&pos_out[cc * 3 + 2], wgt * az);
  }
}

// ---------------- fused node kernel: 32 nodes/block, 8 waves; nmsg f32 ----------------
__global__ __launch_bounds__(512, 4) void node_kernel(
    const __hip_bfloat16* __restrict__ hb, const float* __restrict__ nmsg,
    const __hip_bfloat16* __restrict__ NW1T, const float* __restrict__ nn_b1,
    const __hip_bfloat16* __restrict__ NW2T, const float* __restrict__ nn_b2,
    const float* __restrict__ nn_g, const float* __restrict__ nn_bt,
    float* __restrict__ out_h) {
  __shared__ __align__(16) __hip_bfloat16 A2[32 * 264];
  __shared__ float red[8][32], redsq[8][32];
  __shared__ float mv[32][2];
  __shared__ float gb[HH], btb[HH];
  const int tid = threadIdx.x, w = tid >> 6, l = tid & 63, r = l & 15, g = l >> 4;
  const int n0 = blockIdx.x * 32;
  if (tid < 256) {
    gb[tid] = nn_g[tid];
    btb[tid] = nn_bt[tid];
  }

  f32x4 acc[2][2];
#pragma unroll
  for (int a = 0; a < 2; ++a)
#pragma unroll
    for (int b = 0; b < 2; ++b) acc[a][b] = (f32x4){0.f, 0.f, 0.f, 0.f};
  for (int ks = 0; ks < 8; ++ks) {
    bf16x8 af[2], bfr[2];
#pragma unroll
    for (int fm = 0; fm < 2; ++fm)
      af[fm] = *(const bf16x8*)(hb + (size_t)(n0 + fm * 16 + r) * 256 + ks * 32 + g * 8);
#pragma unroll
    for (int fn = 0; fn < 2; ++fn)
      bfr[fn] = *(const bf16x8*)(NW1T + (size_t)(w * 32 + fn * 16 + r) * 512 + ks * 32 + g * 8);
#pragma unroll
    for (int fm = 0; fm < 2; ++fm)
#pragma unroll
      for (int fn = 0; fn < 2; ++fn)
        acc[fm][fn] =
            __builtin_amdgcn_mfma_f32_16x16x32_bf16(af[fm], bfr[fn], acc[fm][fn], 0, 0, 0);
  }
  for (int ks = 0; ks < 8; ++ks) {
    bf16x8 af[2], bfr[2];
#pragma unroll
    for (int fm = 0; fm < 2; ++fm) {
      const float* src = nmsg + (size_t)(n0 + fm * 16 + r) * 256 + ks * 32 + g * 8;
      float4 a0 = *(const float4*)src;
      float4 a1 = *(const float4*)(src + 4);
      bf16x8 v;
      v[0] = (__bf16)a0.x;
      v[1] = (__bf16)a0.y;
      v[2] = (__bf16)a0.z;
      v[3] = (__bf16)a0.w;
      v[4] = (__bf16)a1.x;
      v[5] = (__bf16)a1.y;
      v[6] = (__bf16)a1.z;
      v[7] = (__bf16)a1.w;
      af[fm] = v;
    }
#pragma unroll
    for (int fn = 0; fn < 2; ++fn)
      bfr[fn] =
          *(const bf16x8*)(NW1T + (size_t)(w * 32 + fn * 16 + r) * 512 + 256 + ks * 32 + g * 8);
#pragma unroll
    for (int fm = 0; fm < 2; ++fm)
#pragma unroll
      for (int fn = 0; fn < 2; ++fn)
        acc[fm][fn] =
            __builtin_amdgcn_mfma_f32_16x16x32_bf16(af[fm], bfr[fn], acc[fm][fn], 0, 0, 0);
  }
  __syncthreads();
#pragma unroll
  for (int fn = 0; fn < 2; ++fn) {
    int col = w * 32 + fn * 16 + r;
    float b1 = nn_b1[col];
#pragma unroll
    for (int fm = 0; fm < 2; ++fm)
#pragma unroll
      for (int q = 0; q < 4; ++q) {
        int row = fm * 16 + g * 4 + q;
        A2[row * 264 + col] = __float2bfloat16(silu_f(acc[fm][fn][q] + b1));
      }
  }
  __syncthreads();

#pragma unroll
  for (int a = 0; a < 2; ++a)
#pragma unroll
    for (int b = 0; b < 2; ++b) acc[a][b] = (f32x4){0.f, 0.f, 0.f, 0.f};
  for (int ks = 0; ks < 8; ++ks) {
    bf16x8 af[2], bfr[2];
#pragma unroll
    for (int fm = 0; fm < 2; ++fm)
      af[fm] = *(const bf16x8*)(A2 + (fm * 16 + r) * 264 + ks * 32 + g * 8);
#pragma unroll
    for (int fn = 0; fn < 2; ++fn)
      bfr[fn] = *(const bf16x8*)(NW2T + (size_t)(w * 32 + fn * 16 + r) * 256 + ks * 32 + g * 8);
#pragma unroll
    for (int fm = 0; fm < 2; ++fm)
#pragma unroll
      for (int fn = 0; fn < 2; ++fn)
        acc[fm][fn] =
            __builtin_amdgcn_mfma_f32_16x16x32_bf16(af[fm], bfr[fn], acc[fm][fn], 0, 0, 0);
  }
#pragma unroll
  for (int fn = 0; fn < 2; ++fn) {
    float b2 = nn_b2[w * 32 + fn * 16 + r];
#pragma unroll
    for (int fm = 0; fm < 2; ++fm)
#pragma unroll
      for (int q = 0; q < 4; ++q) acc[fm][fn][q] += b2;
  }
#pragma unroll
  for (int fm = 0; fm < 2; ++fm)
#pragma unroll
    for (int q = 0; q < 4; ++q) {
      float s = acc[fm][0][q] + acc[fm][1][q];
      float sq = acc[fm][0][q] * acc[fm][0][q] + acc[fm][1][q] * acc[fm][1][q];
#pragma unroll
      for (int m = 1; m < 16; m <<= 1) {
        s += __shfl_xor(s, m, 64);
        sq += __shfl_xor(sq, m, 64);
      }
      if (r == 0) {
        red[w][fm * 16 + g * 4 + q] = s;
        redsq[w][fm * 16 + g * 4 + q] = sq;
      }
    }
  __syncthreads();
  if (tid < 32) {
    float s = 0.f, sq = 0.f;
#pragma unroll
    for (int k = 0; k < 8; ++k) {
      s += red[k][tid];
      sq += redsq[k][tid];
    }
    float mean = s * (1.0f / HH);
    float var = sq * (1.0f / HH) - mean * mean;
    mv[tid][0] = mean;
    mv[tid][1] = rsqrtf(var + 1e-5f);
  }
  __syncthreads();
#pragma unroll
  for (int fn = 0; fn < 2; ++fn) {
    int col = w * 32 + fn * 16 + r;
    float gg = gb[col], bb = btb[col];
#pragma unroll
    for (int fm = 0; fm < 2; ++fm)
#pragma unroll
      for (int q = 0; q < 4; ++q) {
        int row = fm * 16 + g * 4 + q;
        out_h[(size_t)(n0 + row) * HH + col] =
            (acc[fm][fn][q] - mv[row][0]) * mv[row][1] * gg + bb;
      }
  }
}

// ---------------- launch ----------------
extern "C" void kernel_launch(void* const* d_in, const int* in_sizes, int n_in,
                              void* d_out, int out_size, void* d_ws, size_t ws_size,
                              hipStream_t stream) {
  const float* h = (const float*)d_in[0];
  const float* pos = (const float*)d_in[1];
  const float* rb_w1 = (const float*)d_in[2];
  const float* rb_b1 = (const float*)d_in[3];
  const float* rb_w2 = (const float*)d_in[4];
  const float* rb_b2 = (const float*)d_in[5];
  const float* en_w1 = (const float*)d_in[6];
  const float* en_b1 = (const float*)d_in[7];
  const float* en_w2 = (const float*)d_in[8];
  const float* en_b2 = (const float*)d_in[9];
  const float* en_g = (const float*)d_in[10];
  const float* en_bt = (const float*)d_in[11];
  const float* nn_w1 = (const float*)d_in[12];
  const float* nn_b1 = (const float*)d_in[13];
  const float* nn_w2 = (const float*)d_in[14];
  const float* nn_b2 = (const float*)d_in[15];
  const float* nn_g = (const float*)d_in[16];
  const float* nn_bt = (const float*)d_in[17];
  const float* cn_w1 = (const float*)d_in[18];
  const float* cn_b1 = (const float*)d_in[19];
  const float* cn_w2 = (const float*)d_in[20];
  const float* cn_b2 = (const float*)d_in[21];
  const int* ei = (const int*)d_in[22];

  float* out_h = (float*)d_out;
  float* out_pos = out_h + (size_t)NN * HH;

  char* p = (char*)d_ws;
  auto alloc = [&p](size_t bytes) {
    char* q = p;
    p += (bytes + 255) & ~(size_t)255;
    return q;
  };
  __hip_bfloat16* hb = (__hip_bfloat16*)alloc((size_t)NN * HH * 2);
  __hip_bfloat16* Pb = (__hip_bfloat16*)alloc((size_t)NN * 512 * 2);
  __hip_bfloat16* W1abT = (__hip_bfloat16*)alloc((size_t)512 * 256 * 2);
  __hip_bfloat16* W2T = (__hip_bfloat16*)alloc((size_t)256 * 256 * 2);
  __hip_bfloat16* NW1T = (__hip_bfloat16*)alloc((size_t)256 * 512 * 2);
  __hip_bfloat16* NW2T = (__hip_bfloat16*)alloc((size_t)256 * 256 * 2);
  __hip_bfloat16* CW1T = (__hip_bfloat16*)alloc((size_t)128 * 256 * 2);
  __hip_bfloat16* RWT = (__hip_bfloat16*)alloc((size_t)256 * 32 * 2);
  float* b1p = (float*)alloc((size_t)256 * 4);
  float* nmsg = (float*)alloc((size_t)NN * HH * 4);
  int* counts = (int*)alloc((size_t)NN * 4);
  int* offs = (int*)alloc((size_t)(NN + 1) * 4);
  int* cursor = (int*)alloc((size_t)NN * 4);
  int* elist = (int*)alloc((size_t)EE * 4);
  int* bsum = (int*)alloc((size_t)64 * 4);
  int* bbase = (int*)alloc((size_t)64 * 4);

  hipMemsetAsync(out_pos, 0, (size_t)NN * 3 * sizeof(float), stream);
  hipMemsetAsync(counts, 0, (size_t)NN * sizeof(int), stream);
  hipMemsetAsync(nmsg, 0, (size_t)NN * HH * sizeof(float), stream);

  prep_w_kernel<<<1697, 256, 0, stream>>>(en_w1, en_w2, nn_w1, nn_w2, cn_w1, rb_w2, rb_b2,
                                          en_b1, W2T, NW1T, NW2T, CW1T, W1abT, RWT, b1p);
  conv_h_kernel<<<(NN * HH / 4 + 255) / 256, 256, 0, stream>>>(h, hb, NN * HH / 4);
  count_kernel<<<EE / 256, 256, 0, stream>>>(ei, counts);
  scanA_kernel<<<NN / 256, 256, 0, stream>>>(counts, bsum);
  scanB_kernel<<<1, 64, 0, stream>>>(bsum, bbase, offs);
  scanC_kernel<<<NN / 256, 256, 0, stream>>>(counts, bbase, offs, cursor);
  scatter_kernel<<<EE / 256, 256, 0, stream>>>(ei, cursor, elist);
  pgemm_kernel<<<NN / 64, 512, 0, stream>>>(hb, W1abT, Pb);
  edge_kernel<<<EE / 32, 512, 0, stream>>>(Pb, ei, pos, rb_w1, rb_b1, RWT, b1p, W2T, en_b2,
                                           en_g, en_bt, CW1T, cn_b1, cn_w2, cn_b2, elist,
                                           nmsg, out_pos);
  node_kernel<<<NN / 32, 512, 0, stream>>>(hb, nmsg, NW1T, nn_b1, NW2T, nn_b2, nn_g, nn_bt,
                                           out_h);
}

// Round 9
// 480.234 us; speedup vs baseline: 1.1028x; 1.1028x over previous
//
#include <hip/hip_runtime.h>
#include <hip/hip_bf16.h>

// ---------------------------------------------------------------------------
// EGNN layer, v9: R7 structure (best: 492us) + T14 async staging preload in
// edge_kernel (P-gathers issued under rad-MFMA) + fused prep kernel.
// ---------------------------------------------------------------------------

#define NN 16384
#define EE 262144
#define HH 256
#define RR 32

typedef __bf16 bf16x8 __attribute__((ext_vector_type(8)));
typedef float f32x4 __attribute__((ext_vector_type(4)));

__device__ __forceinline__ float silu_f(float x) { return x / (1.0f + __expf(-x)); }

__device__ __forceinline__ unsigned short bf_bits(float x) {
  union { __hip_bfloat16 b; unsigned short u; } v;
  v.b = __float2bfloat16(x);
  return v.u;
}
__device__ __forceinline__ float ubf(unsigned short u) {
  return __uint_as_float(((unsigned)u) << 16);
}

// ---------------- fused prep: conv_h (4096) + count (1024) + weights (1697) ----------------
__global__ __launch_bounds__(256) void prep_all_kernel(
    const float* __restrict__ h, const int* __restrict__ ei,
    const float* __restrict__ en_w1, const float* __restrict__ en_w2,
    const float* __restrict__ nn_w1, const float* __restrict__ nn_w2,
    const float* __restrict__ cn_w1, const float* __restrict__ rb_w2,
    const float* __restrict__ rb_b2, const float* __restrict__ en_b1,
    __hip_bfloat16* __restrict__ hb, __hip_bfloat16* __restrict__ W2T,
    __hip_bfloat16* __restrict__ NW1T, __hip_bfloat16* __restrict__ NW2T,
    __hip_bfloat16* __restrict__ CW1T, __hip_bfloat16* __restrict__ W1abT,
    __hip_bfloat16* __restrict__ RWT, float* __restrict__ b1p,
    int* __restrict__ counts) {
  int bid = blockIdx.x, tid = threadIdx.x;
  if (bid < 4096) {  // conv_h: float4 -> 4x bf16
    int i = bid * 256 + tid;
    float4 v = ((const float4*)h)[i];
    __hip_bfloat16* d = hb + (size_t)i * 4;
    d[0] = __float2bfloat16(v.x);
    d[1] = __float2bfloat16(v.y);
    d[2] = __float2bfloat16(v.z);
    d[3] = __float2bfloat16(v.w);
    return;
  }
  if (bid < 5120) {  // count
    int e = (bid - 4096) * 256 + tid;
    atomicAdd(&counts[ei[EE + e]], 1);
    return;
  }
  int b2 = bid - 5120;
  if (b2 < 256) {
    int i = b2 * 256 + tid, k = i >> 8, c = i & 255;
    W2T[(size_t)c * 256 + k] = __float2bfloat16(en_w2[i]);
  } else if (b2 < 768) {
    int i = (b2 - 256) * 256 + tid, k = i >> 8, c = i & 255;
    NW1T[(size_t)c * 512 + k] = __float2bfloat16(nn_w1[i]);
  } else if (b2 < 1024) {
    int i = (b2 - 768) * 256 + tid, k = i >> 8, c = i & 255;
    NW2T[(size_t)c * 256 + k] = __float2bfloat16(nn_w2[i]);
  } else if (b2 < 1152) {
    int i = (b2 - 1024) * 256 + tid, k = i >> 7, c = i & 127;
    CW1T[(size_t)c * 256 + k] = __float2bfloat16(cn_w1[i]);
  } else if (b2 < 1408) {
    int i = (b2 - 1152) * 256 + tid, k = i >> 8, c = i & 255;
    W1abT[(size_t)c * 256 + k] = __float2bfloat16(en_w1[i]);
  } else if (b2 < 1664) {
    int i = (b2 - 1408) * 256 + tid, k = i >> 8, c = i & 255;
    W1abT[(size_t)(256 + c) * 256 + k] = __float2bfloat16(en_w1[256 * 256 + i]);
  } else if (b2 < 1696) {
    int t = (b2 - 1664) * 256 + tid;
    int c = t >> 5, i = t & 31;
    float s = 0.f;
#pragma unroll
    for (int j = 0; j < 32; ++j) s += rb_w2[i * 32 + j] * en_w1[(512 + j) * 256 + c];
    RWT[c * 32 + i] = __float2bfloat16(s);
  } else {
    int c = tid;
    float s = en_b1[c];
#pragma unroll
    for (int j = 0; j < 32; ++j) s += rb_b2[j] * en_w1[(512 + j) * 256 + c];
    b1p[c] = s;
  }
}

// ---------------- CSR scan + scatter ----------------
__global__ __launch_bounds__(256) void scanA_kernel(const int* __restrict__ counts,
                                                    int* __restrict__ bsum) {
  __shared__ int ws[4];
  int t = threadIdx.x;
  int v = counts[blockIdx.x * 256 + t];
#pragma unroll
  for (int m = 1; m < 64; m <<= 1) v += __shfl_xor(v, m, 64);
  if ((t & 63) == 0) ws[t >> 6] = v;
  __syncthreads();
  if (t == 0) bsum[blockIdx.x] = ws[0] + ws[1] + ws[2] + ws[3];
}

__global__ __launch_bounds__(64) void scanB_kernel(const int* __restrict__ bsum,
                                                   int* __restrict__ bbase,
                                                   int* __restrict__ offs) {
  int t = threadIdx.x;
  int v = bsum[t], x = v;
#pragma unroll
  for (int d = 1; d < 64; d <<= 1) {
    int y = __shfl_up(x, d, 64);
    if (t >= d) x += y;
  }
  bbase[t] = x - v;
  if (t == 63) offs[NN] = x;
}

__global__ __launch_bounds__(256) void scanC_kernel(const int* __restrict__ counts,
                                                    const int* __restrict__ bbase,
                                                    int* __restrict__ offs,
                                                    int* __restrict__ cursor) {
  __shared__ int wtot[4];
  int t = threadIdx.x, wv = t >> 6, ln = t & 63;
  int base = blockIdx.x * 256;
  int v = counts[base + t], x = v;
#pragma unroll
  for (int d = 1; d < 64; d <<= 1) {
    int y = __shfl_up(x, d, 64);
    if (ln >= d) x += y;
  }
  if (ln == 63) wtot[wv] = x;
  __syncthreads();
  int add = bbase[blockIdx.x];
  for (int k = 0; k < wv; ++k) add += wtot[k];
  int excl = add + x - v;
  offs[base + t] = excl;
  cursor[base + t] = excl;
}

__global__ __launch_bounds__(256) void scatter_kernel(const int* __restrict__ ei,
                                                      int* __restrict__ cursor,
                                                      int* __restrict__ elist) {
  int e = blockIdx.x * 256 + threadIdx.x;
  if (e >= EE) return;
  int c = ei[EE + e];
  int p = atomicAdd(&cursor[c], 1);
  elist[p] = e;
}

// ---------------- P = h @ [W1a|W1b] : [N,512] bf16 ----------------
__global__ __launch_bounds__(512) void pgemm_kernel(const __hip_bfloat16* __restrict__ A,
                                                    const __hip_bfloat16* __restrict__ BT,
                                                    __hip_bfloat16* __restrict__ out) {
  const int tid = threadIdx.x, w = tid >> 6, l = tid & 63, r = l & 15, g = l >> 4;
  const int n0 = blockIdx.x * 64;
  f32x4 acc[4][4];
#pragma unroll
  for (int a = 0; a < 4; ++a)
#pragma unroll
    for (int b = 0; b < 4; ++b) acc[a][b] = (f32x4){0.f, 0.f, 0.f, 0.f};
  for (int ks = 0; ks < 8; ++ks) {
    bf16x8 af[4], bfr[4];
#pragma unroll
    for (int fm = 0; fm < 4; ++fm)
      af[fm] = *(const bf16x8*)(A + (size_t)(n0 + fm * 16 + r) * 256 + ks * 32 + g * 8);
#pragma unroll
    for (int fn = 0; fn < 4; ++fn)
      bfr[fn] = *(const bf16x8*)(BT + (size_t)(w * 64 + fn * 16 + r) * 256 + ks * 32 + g * 8);
#pragma unroll
    for (int fm = 0; fm < 4; ++fm)
#pragma unroll
      for (int fn = 0; fn < 4; ++fn)
        acc[fm][fn] =
            __builtin_amdgcn_mfma_f32_16x16x32_bf16(af[fm], bfr[fn], acc[fm][fn], 0, 0, 0);
  }
#pragma unroll
  for (int fm = 0; fm < 4; ++fm)
#pragma unroll
    for (int fn = 0; fn < 4; ++fn) {
      int col = w * 64 + fn * 16 + r;
#pragma unroll
      for (int q = 0; q < 4; ++q) {
        int row = n0 + fm * 16 + g * 4 + q;
        out[(size_t)row * 512 + col] = __float2bfloat16(acc[fm][fn][q]);
      }
    }
}

// ---------------- fused edge kernel (CSR order), R7 structure + T14 preload ----------------
// 64 CSR slots/block, 512 threads (8 waves).
__global__ __launch_bounds__(512, 4) void edge_kernel(
    const __hip_bfloat16* __restrict__ Pb, const int* __restrict__ ei,
    const float* __restrict__ pos, const float* __restrict__ rb_w1,
    const float* __restrict__ rb_b1, const __hip_bfloat16* __restrict__ RWT,
    const float* __restrict__ b1p, const __hip_bfloat16* __restrict__ W2T,
    const float* __restrict__ en_b2, const float* __restrict__ en_g,
    const float* __restrict__ en_bt, const __hip_bfloat16* __restrict__ CW1T,
    const float* __restrict__ cn_b1, const float* __restrict__ cn_w2,
    const float* __restrict__ cn_b2, const int* __restrict__ elist,
    float* __restrict__ nmsg, float* __restrict__ pos_out) {
  __shared__ __align__(16) __hip_bfloat16 A2[64 * 264];  // rad -> hidden -> msg
  __shared__ float relb[64][3];
  __shared__ float distb[64];
  __shared__ int srow[64], scol[64];
  __shared__ float red[8][64], redsq[8][64];
  __shared__ float mv[64][2];
  __shared__ float cb1b[128], cw2b[128];

  const int tid = threadIdx.x, w = tid >> 6, l = tid & 63, r = l & 15, g = l >> 4;
  const int e0 = blockIdx.x * 64;

  if (tid < 128) {
    cb1b[tid] = cn_b1[tid];
    cw2b[tid] = cn_w2[tid];
  }
  if (tid < 64) {
    int e = elist[e0 + tid];
    int r2 = ei[e], c2 = ei[EE + e];
    srow[tid] = r2;
    scol[tid] = c2;
    float dx = pos[c2 * 3 + 0] - pos[r2 * 3 + 0];
    float dy = pos[c2 * 3 + 1] - pos[r2 * 3 + 1];
    float dz = pos[c2 * 3 + 2] - pos[r2 * 3 + 2];
    relb[tid][0] = dx;
    relb[tid][1] = dy;
    relb[tid][2] = dz;
    float ex = dx + 1e-8f, ey = dy + 1e-8f, ez = dz + 1e-8f;
    distb[tid] = sqrtf(ex * ex + ey * ey + ez * ez);
  }
  __syncthreads();  // #1: meta ready

  // ---- T14: issue staging P-gathers NOW; latency hides under rad pre-pass ----
  bf16x8 p1r[4], p2r[4];
#pragma unroll
  for (int it = 0; it < 4; ++it) {
    int ch = it * 512 + tid;  // 2048 chunks of 8 elems
    int i = ch >> 5, c = ch & 31;
    p1r[it] = *(const bf16x8*)(Pb + (size_t)srow[i] * 512 + c * 8);
    p2r[it] = *(const bf16x8*)(Pb + (size_t)scol[i] * 512 + 256 + c * 8);
  }

  // ---- rad pre-pass (transposed MFMA), packed bf16 writes into A2 ----
  unsigned short* A2u = (unsigned short*)A2;
  {
    const int eloc = (w & 3) * 16 + r;
    const int chalf = w >> 2;
    float d = distb[eloc];
    bf16x8 sfrag;
#pragma unroll
    for (int j = 0; j < 8; ++j) {
      float x = d * rb_w1[g * 8 + j] + rb_b1[g * 8 + j];
      sfrag[j] = (__bf16)silu_f(x);
    }
#pragma unroll
    for (int t = 0; t < 8; ++t) {
      int cblk = chalf * 8 + t;
      int cbase = cblk * 16 + g * 4;
      bf16x8 afr = *(const bf16x8*)(RWT + (size_t)(cblk * 16 + r) * 32 + g * 8);
      f32x4 rad = __builtin_amdgcn_mfma_f32_16x16x32_bf16(
          afr, sfrag, (f32x4){0.f, 0.f, 0.f, 0.f}, 0, 0, 0);
      ushort4 o;
      o.x = bf_bits(rad[0]);
      o.y = bf_bits(rad[1]);
      o.z = bf_bits(rad[2]);
      o.w = bf_bits(rad[3]);
      *(ushort4*)(A2u + (size_t)eloc * 264 + cbase) = o;
    }
  }
  __syncthreads();  // #2: rad in A2

  // ---- staging: hidden = silu(rad + P1 + P2 + b1p) using preloaded P ----
#pragma unroll
  for (int it = 0; it < 4; ++it) {
    int ch = it * 512 + tid;
    int i = ch >> 5, c = ch & 31;
    bf16x8 radv = *(const bf16x8*)(A2 + i * 264 + c * 8);
    bf16x8 p1 = p1r[it], p2 = p2r[it];
    float4 b1a = *(const float4*)(b1p + c * 8);
    float4 b1b = *(const float4*)(b1p + c * 8 + 4);
    float bv[8] = {b1a.x, b1a.y, b1a.z, b1a.w, b1b.x, b1b.y, b1b.z, b1b.w};
    bf16x8 o;
#pragma unroll
    for (int j = 0; j < 8; ++j)
      o[j] = (__bf16)silu_f((float)radv[j] + (float)p1[j] + (float)p2[j] + bv[j]);
    *(bf16x8*)(A2 + i * 264 + c * 8) = o;
  }
  __syncthreads();  // #3: hidden ready

  // ---- GEMM2 (transposed): D[c'][e], A=W2T rows, B=A2 rows ----
  f32x4 acc[2][4];
#pragma unroll
  for (int a = 0; a < 2; ++a)
#pragma unroll
    for (int b = 0; b < 4; ++b) acc[a][b] = (f32x4){0.f, 0.f, 0.f, 0.f};
  for (int ks = 0; ks < 8; ++ks) {
    bf16x8 af[2], bfr[4];
#pragma unroll
    for (int mf = 0; mf < 2; ++mf)
      af[mf] = *(const bf16x8*)(W2T + (size_t)(w * 32 + mf * 16 + r) * 256 + ks * 32 + g * 8);
#pragma unroll
    for (int nf = 0; nf < 4; ++nf)
      bfr[nf] = *(const bf16x8*)(A2 + (nf * 16 + r) * 264 + ks * 32 + g * 8);
#pragma unroll
    for (int mf = 0; mf < 2; ++mf)
#pragma unroll
      for (int nf = 0; nf < 4; ++nf)
        acc[mf][nf] =
            __builtin_amdgcn_mfma_f32_16x16x32_bf16(af[mf], bfr[nf], acc[mf][nf], 0, 0, 0);
  }
  {
    float4 b2v0 = *(const float4*)(en_b2 + w * 32 + g * 4);
    float4 b2v1 = *(const float4*)(en_b2 + w * 32 + 16 + g * 4);
#pragma unroll
    for (int nf = 0; nf < 4; ++nf) {
      acc[0][nf][0] += b2v0.x;
      acc[0][nf][1] += b2v0.y;
      acc[0][nf][2] += b2v0.z;
      acc[0][nf][3] += b2v0.w;
      acc[1][nf][0] += b2v1.x;
      acc[1][nf][1] += b2v1.y;
      acc[1][nf][2] += b2v1.z;
      acc[1][nf][3] += b2v1.w;
    }
  }

  // ---- LN stats ----
#pragma unroll
  for (int nf = 0; nf < 4; ++nf) {
    float s = 0.f, sq = 0.f;
#pragma unroll
    for (int mf = 0; mf < 2; ++mf)
#pragma unroll
      for (int q = 0; q < 4; ++q) {
        float v = acc[mf][nf][q];
        s += v;
        sq += v * v;
      }
    s += __shfl_xor(s, 16, 64);
    s += __shfl_xor(s, 32, 64);
    sq += __shfl_xor(sq, 16, 64);
    sq += __shfl_xor(sq, 32, 64);
    if (l < 16) {
      red[w][nf * 16 + l] = s;
      redsq[w][nf * 16 + l] = sq;
    }
  }
  __syncthreads();  // #4
  if (tid < 64) {
    float s = 0.f, sq = 0.f;
#pragma unroll
    for (int k = 0; k < 8; ++k) {
      s += red[k][tid];
      sq += redsq[k][tid];
    }
    float mean = s * (1.0f / HH);
    float var = sq * (1.0f / HH) - mean * mean;
    mv[tid][0] = mean;
    mv[tid][1] = rsqrtf(var + 1e-5f);
  }
  __syncthreads();  // #5

  // ---- LN apply: packed ushort4 writes into A2 ----
  {
    float4 gv0 = *(const float4*)(en_g + w * 32 + g * 4);
    float4 gv1 = *(const float4*)(en_g + w * 32 + 16 + g * 4);
    float4 bv0 = *(const float4*)(en_bt + w * 32 + g * 4);
    float4 bv1 = *(const float4*)(en_bt + w * 32 + 16 + g * 4);
#pragma unroll
    for (int nf = 0; nf < 4; ++nf) {
      int e = nf * 16 + r;
      float mm = mv[e][0], rs = mv[e][1];
      ushort4 o0, o1;
      o0.x = bf_bits((acc[0][nf][0] - mm) * rs * gv0.x + bv0.x);
      o0.y = bf_bits((acc[0][nf][1] - mm) * rs * gv0.y + bv0.y);
      o0.z = bf_bits((acc[0][nf][2] - mm) * rs * gv0.z + bv0.z);
      o0.w = bf_bits((acc[0][nf][3] - mm) * rs * gv0.w + bv0.w);
      o1.x = bf_bits((acc[1][nf][0] - mm) * rs * gv1.x + bv1.x);
      o1.y = bf_bits((acc[1][nf][1] - mm) * rs * gv1.y + bv1.y);
      o1.z = bf_bits((acc[1][nf][2] - mm) * rs * gv1.z + bv1.z);
      o1.w = bf_bits((acc[1][nf][3] - mm) * rs * gv1.w + bv1.w);
      *(ushort4*)(A2u + (size_t)e * 264 + w * 32 + g * 4) = o0;
      *(ushort4*)(A2u + (size_t)e * 264 + w * 32 + 16 + g * 4) = o1;
    }
  }
  __syncthreads();  // #6: msg ready in A2

  // ---- segmented nmsg reduction (lane-contiguous; plain stores interior) ----
  {
    int c = tid & 255, h = tid >> 8;
    int rbeg = h * 32, rend = rbeg + 32;
    int segstart = rbeg;
    int cur = scol[rbeg];
    float run = 0.f;
    for (int row = rbeg; row < rend; ++row) {
      int nd = scol[row];
      if (nd != cur) {
        float* dst = &nmsg[(size_t)cur * 256 + c];
        if (segstart > rbeg)
          *dst = run;  // interior segment: exclusive by CSR contiguity
        else
          atomicAdd(dst, run);
        segstart = row;
        cur = nd;
        run = 0.f;
      }
      run += ubf(A2u[(size_t)row * 264 + c]);
    }
    atomicAdd(&nmsg[(size_t)cur * 256 + c], run);
  }

  // ---- coord head (R4 orientation): D[e][c'], af = msg rows, bf = CW1T row ----
  f32x4 c2a[4];
#pragma unroll
  for (int a = 0; a < 4; ++a) c2a[a] = (f32x4){0.f, 0.f, 0.f, 0.f};
  for (int ks = 0; ks < 8; ++ks) {
    bf16x8 af[4];
#pragma unroll
    for (int fm = 0; fm < 4; ++fm)
      af[fm] = *(const bf16x8*)(A2 + (fm * 16 + r) * 264 + ks * 32 + g * 8);
    bf16x8 bfr = *(const bf16x8*)(CW1T + (size_t)(w * 16 + r) * 256 + ks * 32 + g * 8);
#pragma unroll
    for (int fm = 0; fm < 4; ++fm)
      c2a[fm] = __builtin_amdgcn_mfma_f32_16x16x32_bf16(af[fm], bfr, c2a[fm], 0, 0, 0);
  }
  {
    int ccol = w * 16 + r;
    float cb = cb1b[ccol], cw = cw2b[ccol];
#pragma unroll
    for (int fm = 0; fm < 4; ++fm)
#pragma unroll
      for (int q = 0; q < 4; ++q) {
        float v = silu_f(c2a[fm][q] + cb) * cw;
#pragma unroll
        for (int m = 1; m < 16; m <<= 1) v += __shfl_xor(v, m, 64);
        if (r == 0) red[w][fm * 16 + g * 4 + q] = v;
      }
  }
  __syncthreads();  // #7
  if (tid < 64) {
    float s = cn_b2[0];
#pragma unroll
    for (int k = 0; k < 8; ++k) s += red[k][tid];
    float wgt = tanhf(s);
    float ax = relb[tid][0], ay = relb[tid][1], az = relb[tid][2];
    int rr = srow[tid], cc = scol[tid];
    atomicAdd(&pos_out[rr * 3 + 0], -wgt * ax);
    atomicAdd(&pos_out[rr * 3 + 1], -wgt * ay);
    atomicAdd(&pos_out[rr * 3 + 2], -wgt * az);
    atomicAdd(&pos_out[cc * 3 + 0], wgt * ax);
    atomicAdd(&pos_out[cc * 3 + 1], wgt * ay);
    atomicAdd(&pos_out[cc * 3 + 2], wgt * az);
  }
}

// ---------------- fused node kernel: 32 nodes/block, 8 waves; nmsg f32 ----------------
__global__ __launch_bounds__(512, 4) void node_kernel(
    const __hip_bfloat16* __restrict__ hb, const float* __restrict__ nmsg,
    const __hip_bfloat16* __restrict__ NW1T, const float* __restrict__ nn_b1,
    const __hip_bfloat16* __restrict__ NW2T, const float* __restrict__ nn_b2,
    const float* __restrict__ nn_g, const float* __restrict__ nn_bt,
    float* __restrict__ out_h) {
  __shared__ __align__(16) __hip_bfloat16 A2[32 * 264];
  __shared__ float red[8][32], redsq[8][32];
  __shared__ float mv[32][2];
  __shared__ float gb[HH], btb[HH];
  const int tid = threadIdx.x, w = tid >> 6, l = tid & 63, r = l & 15, g = l >> 4;
  const int n0 = blockIdx.x * 32;
  if (tid < 256) {
    gb[tid] = nn_g[tid];
    btb[tid] = nn_bt[tid];
  }

  f32x4 acc[2][2];
#pragma unroll
  for (int a = 0; a < 2; ++a)
#pragma unroll
    for (int b = 0; b < 2; ++b) acc[a][b] = (f32x4){0.f, 0.f, 0.f, 0.f};
  for (int ks = 0; ks < 8; ++ks) {
    bf16x8 af[2], bfr[2];
#pragma unroll
    for (int fm = 0; fm < 2; ++fm)
      af[fm] = *(const bf16x8*)(hb + (size_t)(n0 + fm * 16 + r) * 256 + ks * 32 + g * 8);
#pragma unroll
    for (int fn = 0; fn < 2; ++fn)
      bfr[fn] = *(const bf16x8*)(NW1T + (size_t)(w * 32 + fn * 16 + r) * 512 + ks * 32 + g * 8);
#pragma unroll
    for (int fm = 0; fm < 2; ++fm)
#pragma unroll
      for (int fn = 0; fn < 2; ++fn)
        acc[fm][fn] =
            __builtin_amdgcn_mfma_f32_16x16x32_bf16(af[fm], bfr[fn], acc[fm][fn], 0, 0, 0);
  }
  for (int ks = 0; ks < 8; ++ks) {
    bf16x8 af[2], bfr[2];
#pragma unroll
    for (int fm = 0; fm < 2; ++fm) {
      const float* src = nmsg + (size_t)(n0 + fm * 16 + r) * 256 + ks * 32 + g * 8;
      float4 a0 = *(const float4*)src;
      float4 a1 = *(const float4*)(src + 4);
      bf16x8 v;
      v[0] = (__bf16)a0.x;
      v[1] = (__bf16)a0.y;
      v[2] = (__bf16)a0.z;
      v[3] = (__bf16)a0.w;
      v[4] = (__bf16)a1.x;
      v[5] = (__bf16)a1.y;
      v[6] = (__bf16)a1.z;
      v[7] = (__bf16)a1.w;
      af[fm] = v;
    }
#pragma unroll
    for (int fn = 0; fn < 2; ++fn)
      bfr[fn] =
          *(const bf16x8*)(NW1T + (size_t)(w * 32 + fn * 16 + r) * 512 + 256 + ks * 32 + g * 8);
#pragma unroll
    for (int fm = 0; fm < 2; ++fm)
#pragma unroll
      for (int fn = 0; fn < 2; ++fn)
        acc[fm][fn] =
            __builtin_amdgcn_mfma_f32_16x16x32_bf16(af[fm], bfr[fn], acc[fm][fn], 0, 0, 0);
  }
  __syncthreads();
#pragma unroll
  for (int fn = 0; fn < 2; ++fn) {
    int col = w * 32 + fn * 16 + r;
    float b1 = nn_b1[col];
#pragma unroll
    for (int fm = 0; fm < 2; ++fm)
#pragma unroll
      for (int q = 0; q < 4; ++q) {
        int row = fm * 16 + g * 4 + q;
        A2[row * 264 + col] = __float2bfloat16(silu_f(acc[fm][fn][q] + b1));
      }
  }
  __syncthreads();

#pragma unroll
  for (int a = 0; a < 2; ++a)
#pragma unroll
    for (int b = 0; b < 2; ++b) acc[a][b] = (f32x4){0.f, 0.f, 0.f, 0.f};
  for (int ks = 0; ks < 8; ++ks) {
    bf16x8 af[2], bfr[2];
#pragma unroll
    for (int fm = 0; fm < 2; ++fm)
      af[fm] = *(const bf16x8*)(A2 + (fm * 16 + r) * 264 + ks * 32 + g * 8);
#pragma unroll
    for (int fn = 0; fn < 2; ++fn)
      bfr[fn] = *(const bf16x8*)(NW2T + (size_t)(w * 32 + fn * 16 + r) * 256 + ks * 32 + g * 8);
#pragma unroll
    for (int fm = 0; fm < 2; ++fm)
#pragma unroll
      for (int fn = 0; fn < 2; ++fn)
        acc[fm][fn] =
            __builtin_amdgcn_mfma_f32_16x16x32_bf16(af[fm], bfr[fn], acc[fm][fn], 0, 0, 0);
  }
#pragma unroll
  for (int fn = 0; fn < 2; ++fn) {
    float b2 = nn_b2[w * 32 + fn * 16 + r];
#pragma unroll
    for (int fm = 0; fm < 2; ++fm)
#pragma unroll
      for (int q = 0; q < 4; ++q) acc[fm][fn][q] += b2;
  }
#pragma unroll
  for (int fm = 0; fm < 2; ++fm)
#pragma unroll
    for (int q = 0; q < 4; ++q) {
      float s = acc[fm][0][q] + acc[fm][1][q];
      float sq = acc[fm][0][q] * acc[fm][0][q] + acc[fm][1][q] * acc[fm][1][q];
#pragma unroll
      for (int m = 1; m < 16; m <<= 1) {
        s += __shfl_xor(s, m, 64);
        sq += __shfl_xor(sq, m, 64);
      }
      if (r == 0) {
        red[w][fm * 16 + g * 4 + q] = s;
        redsq[w][fm * 16 + g * 4 + q] = sq;
      }
    }
  __syncthreads();
  if (tid < 32) {
    float s = 0.f, sq = 0.f;
#pragma unroll
    for (int k = 0; k < 8; ++k) {
      s += red[k][tid];
      sq += redsq[k][tid];
    }
    float mean = s * (1.0f / HH);
    float var = sq * (1.0f / HH) - mean * mean;
    mv[tid][0] = mean;
    mv[tid][1] = rsqrtf(var + 1e-5f);
  }
  __syncthreads();
#pragma unroll
  for (int fn = 0; fn < 2; ++fn) {
    int col = w * 32 + fn * 16 + r;
    float gg = gb[col], bb = btb[col];
#pragma unroll
    for (int fm = 0; fm < 2; ++fm)
#pragma unroll
      for (int q = 0; q < 4; ++q) {
        int row = fm * 16 + g * 4 + q;
        out_h[(size_t)(n0 + row) * HH + col] =
            (acc[fm][fn][q] - mv[row][0]) * mv[row][1] * gg + bb;
      }
  }
}

// ---------------- launch ----------------
extern "C" void kernel_launch(void* const* d_in, const int* in_sizes, int n_in,
                              void* d_out, int out_size, void* d_ws, size_t ws_size,
                              hipStream_t stream) {
  const float* h = (const float*)d_in[0];
  const float* pos = (const float*)d_in[1];
  const float* rb_w1 = (const float*)d_in[2];
  const float* rb_b1 = (const float*)d_in[3];
  const float* rb_w2 = (const float*)d_in[4];
  const float* rb_b2 = (const float*)d_in[5];
  const float* en_w1 = (const float*)d_in[6];
  const float* en_b1 = (const float*)d_in[7];
  const float* en_w2 = (const float*)d_in[8];
  const float* en_b2 = (const float*)d_in[9];
  const float* en_g = (const float*)d_in[10];
  const float* en_bt = (const float*)d_in[11];
  const float* nn_w1 = (const float*)d_in[12];
  const float* nn_b1 = (const float*)d_in[13];
  const float* nn_w2 = (const float*)d_in[14];
  const float* nn_b2 = (const float*)d_in[15];
  const float* nn_g = (const float*)d_in[16];
  const float* nn_bt = (const float*)d_in[17];
  const float* cn_w1 = (const float*)d_in[18];
  const float* cn_b1 = (const float*)d_in[19];
  const float* cn_w2 = (const float*)d_in[20];
  const float* cn_b2 = (const float*)d_in[21];
  const int* ei = (const int*)d_in[22];

  float* out_h = (float*)d_out;
  float* out_pos = out_h + (size_t)NN * HH;

  char* p = (char*)d_ws;
  auto alloc = [&p](size_t bytes) {
    char* q = p;
    p += (bytes + 255) & ~(size_t)255;
    return q;
  };
  __hip_bfloat16* hb = (__hip_bfloat16*)alloc((size_t)NN * HH * 2);
  __hip_bfloat16* Pb = (__hip_bfloat16*)alloc((size_t)NN * 512 * 2);
  __hip_bfloat16* W1abT = (__hip_bfloat16*)alloc((size_t)512 * 256 * 2);
  __hip_bfloat16* W2T = (__hip_bfloat16*)alloc((size_t)256 * 256 * 2);
  __hip_bfloat16* NW1T = (__hip_bfloat16*)alloc((size_t)256 * 512 * 2);
  __hip_bfloat16* NW2T = (__hip_bfloat16*)alloc((size_t)256 * 256 * 2);
  __hip_bfloat16* CW1T = (__hip_bfloat16*)alloc((size_t)128 * 256 * 2);
  __hip_bfloat16* RWT = (__hip_bfloat16*)alloc((size_t)256 * 32 * 2);
  float* b1p = (float*)alloc((size_t)256 * 4);
  float* nmsg = (float*)alloc((size_t)NN * HH * 4);
  int* counts = (int*)alloc((size_t)NN * 4);
  int* offs = (int*)alloc((size_t)(NN + 1) * 4);
  int* cursor = (int*)alloc((size_t)NN * 4);
  int* elist = (int*)alloc((size_t)EE * 4);
  int* bsum = (int*)alloc((size_t)64 * 4);
  int* bbase = (int*)alloc((size_t)64 * 4);

  hipMemsetAsync(out_pos, 0, (size_t)NN * 3 * sizeof(float), stream);
  hipMemsetAsync(counts, 0, (size_t)NN * sizeof(int), stream);
  hipMemsetAsync(nmsg, 0, (size_t)NN * HH * sizeof(float), stream);

  prep_all_kernel<<<6817, 256, 0, stream>>>(h, ei, en_w1, en_w2, nn_w1, nn_w2, cn_w1, rb_w2,
                                            rb_b2, en_b1, hb, W2T, NW1T, NW2T, CW1T, W1abT,
                                            RWT, b1p, counts);
  scanA_kernel<<<NN / 256, 256, 0, stream>>>(counts, bsum);
  scanB_kernel<<<1, 64, 0, stream>>>(bsum, bbase, offs);
  scanC_kernel<<<NN / 256, 256, 0, stream>>>(counts, bbase, offs, cursor);
  scatter_kernel<<<EE / 256, 256, 0, stream>>>(ei, cursor, elist);
  pgemm_kernel<<<NN / 64, 512, 0, stream>>>(hb, W1abT, Pb);
  edge_kernel<<<EE / 64, 512, 0, stream>>>(Pb, ei, pos, rb_w1, rb_b1, RWT, b1p, W2T, en_b2,
                                           en_g, en_bt, CW1T, cn_b1, cn_w2, cn_b2, elist,
                                           nmsg, out_pos);
  node_kernel<<<NN / 32, 512, 0, stream>>>(hb, nmsg, NW1T, nn_b1, NW2T, nn_b2, nn_g, nn_bt,
                                           out_h);
}

// Round 10
// 444.922 us; speedup vs baseline: 1.1903x; 1.0794x over previous
//
#include <hip/hip_runtime.h>
#include <hip/hip_bf16.h>

// ---------------------------------------------------------------------------
// EGNN layer, v10: R9 math, edge tile doubled to 128 CSR slots/block
// (amortizes the 7 barriers over 2x edges; 77.5KB LDS -> 2 blocks/CU),
// node tile doubled to 64 nodes/block.
// ---------------------------------------------------------------------------

#define NN 16384
#define EE 262144
#define HH 256
#define RR 32

typedef __bf16 bf16x8 __attribute__((ext_vector_type(8)));
typedef float f32x4 __attribute__((ext_vector_type(4)));

__device__ __forceinline__ float silu_f(float x) { return x / (1.0f + __expf(-x)); }

__device__ __forceinline__ unsigned short bf_bits(float x) {
  union { __hip_bfloat16 b; unsigned short u; } v;
  v.b = __float2bfloat16(x);
  return v.u;
}
__device__ __forceinline__ float ubf(unsigned short u) {
  return __uint_as_float(((unsigned)u) << 16);
}

// ---------------- fused prep: conv_h (4096) + count (1024) + weights (1697) ----------------
__global__ __launch_bounds__(256) void prep_all_kernel(
    const float* __restrict__ h, const int* __restrict__ ei,
    const float* __restrict__ en_w1, const float* __restrict__ en_w2,
    const float* __restrict__ nn_w1, const float* __restrict__ nn_w2,
    const float* __restrict__ cn_w1, const float* __restrict__ rb_w2,
    const float* __restrict__ rb_b2, const float* __restrict__ en_b1,
    __hip_bfloat16* __restrict__ hb, __hip_bfloat16* __restrict__ W2T,
    __hip_bfloat16* __restrict__ NW1T, __hip_bfloat16* __restrict__ NW2T,
    __hip_bfloat16* __restrict__ CW1T, __hip_bfloat16* __restrict__ W1abT,
    __hip_bfloat16* __restrict__ RWT, float* __restrict__ b1p,
    int* __restrict__ counts) {
  int bid = blockIdx.x, tid = threadIdx.x;
  if (bid < 4096) {  // conv_h: float4 -> 4x bf16
    int i = bid * 256 + tid;
    float4 v = ((const float4*)h)[i];
    __hip_bfloat16* d = hb + (size_t)i * 4;
    d[0] = __float2bfloat16(v.x);
    d[1] = __float2bfloat16(v.y);
    d[2] = __float2bfloat16(v.z);
    d[3] = __float2bfloat16(v.w);
    return;
  }
  if (bid < 5120) {  // count
    int e = (bid - 4096) * 256 + tid;
    atomicAdd(&counts[ei[EE + e]], 1);
    return;
  }
  int b2 = bid - 5120;
  if (b2 < 256) {
    int i = b2 * 256 + tid, k = i >> 8, c = i & 255;
    W2T[(size_t)c * 256 + k] = __float2bfloat16(en_w2[i]);
  } else if (b2 < 768) {
    int i = (b2 - 256) * 256 + tid, k = i >> 8, c = i & 255;
    NW1T[(size_t)c * 512 + k] = __float2bfloat16(nn_w1[i]);
  } else if (b2 < 1024) {
    int i = (b2 - 768) * 256 + tid, k = i >> 8, c = i & 255;
    NW2T[(size_t)c * 256 + k] = __float2bfloat16(nn_w2[i]);
  } else if (b2 < 1152) {
    int i = (b2 - 1024) * 256 + tid, k = i >> 7, c = i & 127;
    CW1T[(size_t)c * 256 + k] = __float2bfloat16(cn_w1[i]);
  } else if (b2 < 1408) {
    int i = (b2 - 1152) * 256 + tid, k = i >> 8, c = i & 255;
    W1abT[(size_t)c * 256 + k] = __float2bfloat16(en_w1[i]);
  } else if (b2 < 1664) {
    int i = (b2 - 1408) * 256 + tid, k = i >> 8, c = i & 255;
    W1abT[(size_t)(256 + c) * 256 + k] = __float2bfloat16(en_w1[256 * 256 + i]);
  } else if (b2 < 1696) {
    int t = (b2 - 1664) * 256 + tid;
    int c = t >> 5, i = t & 31;
    float s = 0.f;
#pragma unroll
    for (int j = 0; j < 32; ++j) s += rb_w2[i * 32 + j] * en_w1[(512 + j) * 256 + c];
    RWT[c * 32 + i] = __float2bfloat16(s);
  } else {
    int c = tid;
    float s = en_b1[c];
#pragma unroll
    for (int j = 0; j < 32; ++j) s += rb_b2[j] * en_w1[(512 + j) * 256 + c];
    b1p[c] = s;
  }
}

// ---------------- CSR scan + scatter ----------------
__global__ __launch_bounds__(256) void scanA_kernel(const int* __restrict__ counts,
                                                    int* __restrict__ bsum) {
  __shared__ int ws[4];
  int t = threadIdx.x;
  int v = counts[blockIdx.x * 256 + t];
#pragma unroll
  for (int m = 1; m < 64; m <<= 1) v += __shfl_xor(v, m, 64);
  if ((t & 63) == 0) ws[t >> 6] = v;
  __syncthreads();
  if (t == 0) bsum[blockIdx.x] = ws[0] + ws[1] + ws[2] + ws[3];
}

__global__ __launch_bounds__(64) void scanB_kernel(const int* __restrict__ bsum,
                                                   int* __restrict__ bbase,
                                                   int* __restrict__ offs) {
  int t = threadIdx.x;
  int v = bsum[t], x = v;
#pragma unroll
  for (int d = 1; d < 64; d <<= 1) {
    int y = __shfl_up(x, d, 64);
    if (t >= d) x += y;
  }
  bbase[t] = x - v;
  if (t == 63) offs[NN] = x;
}

__global__ __launch_bounds__(256) void scanC_kernel(const int* __restrict__ counts,
                                                    const int* __restrict__ bbase,
                                                    int* __restrict__ offs,
                                                    int* __restrict__ cursor) {
  __shared__ int wtot[4];
  int t = threadIdx.x, wv = t >> 6, ln = t & 63;
  int base = blockIdx.x * 256;
  int v = counts[base + t], x = v;
#pragma unroll
  for (int d = 1; d < 64; d <<= 1) {
    int y = __shfl_up(x, d, 64);
    if (ln >= d) x += y;
  }
  if (ln == 63) wtot[wv] = x;
  __syncthreads();
  int add = bbase[blockIdx.x];
  for (int k = 0; k < wv; ++k) add += wtot[k];
  int excl = add + x - v;
  offs[base + t] = excl;
  cursor[base + t] = excl;
}

__global__ __launch_bounds__(256) void scatter_kernel(const int* __restrict__ ei,
                                                      int* __restrict__ cursor,
                                                      int* __restrict__ elist) {
  int e = blockIdx.x * 256 + threadIdx.x;
  if (e >= EE) return;
  int c = ei[EE + e];
  int p = atomicAdd(&cursor[c], 1);
  elist[p] = e;
}

// ---------------- P = h @ [W1a|W1b] : [N,512] bf16 ----------------
__global__ __launch_bounds__(512) void pgemm_kernel(const __hip_bfloat16* __restrict__ A,
                                                    const __hip_bfloat16* __restrict__ BT,
                                                    __hip_bfloat16* __restrict__ out) {
  const int tid = threadIdx.x, w = tid >> 6, l = tid & 63, r = l & 15, g = l >> 4;
  const int n0 = blockIdx.x * 64;
  f32x4 acc[4][4];
#pragma unroll
  for (int a = 0; a < 4; ++a)
#pragma unroll
    for (int b = 0; b < 4; ++b) acc[a][b] = (f32x4){0.f, 0.f, 0.f, 0.f};
  for (int ks = 0; ks < 8; ++ks) {
    bf16x8 af[4], bfr[4];
#pragma unroll
    for (int fm = 0; fm < 4; ++fm)
      af[fm] = *(const bf16x8*)(A + (size_t)(n0 + fm * 16 + r) * 256 + ks * 32 + g * 8);
#pragma unroll
    for (int fn = 0; fn < 4; ++fn)
      bfr[fn] = *(const bf16x8*)(BT + (size_t)(w * 64 + fn * 16 + r) * 256 + ks * 32 + g * 8);
#pragma unroll
    for (int fm = 0; fm < 4; ++fm)
#pragma unroll
      for (int fn = 0; fn < 4; ++fn)
        acc[fm][fn] =
            __builtin_amdgcn_mfma_f32_16x16x32_bf16(af[fm], bfr[fn], acc[fm][fn], 0, 0, 0);
  }
#pragma unroll
  for (int fm = 0; fm < 4; ++fm)
#pragma unroll
    for (int fn = 0; fn < 4; ++fn) {
      int col = w * 64 + fn * 16 + r;
#pragma unroll
      for (int q = 0; q < 4; ++q) {
        int row = n0 + fm * 16 + g * 4 + q;
        out[(size_t)row * 512 + col] = __float2bfloat16(acc[fm][fn][q]);
      }
    }
}

// ---------------- fused edge kernel: 128 CSR slots/block, 512 threads ----------------
__global__ __launch_bounds__(512, 4) void edge_kernel(
    const __hip_bfloat16* __restrict__ Pb, const int* __restrict__ ei,
    const float* __restrict__ pos, const float* __restrict__ rb_w1,
    const float* __restrict__ rb_b1, const __hip_bfloat16* __restrict__ RWT,
    const float* __restrict__ b1p, const __hip_bfloat16* __restrict__ W2T,
    const float* __restrict__ en_b2, const float* __restrict__ en_g,
    const float* __restrict__ en_bt, const __hip_bfloat16* __restrict__ CW1T,
    const float* __restrict__ cn_b1, const float* __restrict__ cn_w2,
    const float* __restrict__ cn_b2, const int* __restrict__ elist,
    float* __restrict__ nmsg, float* __restrict__ pos_out) {
  __shared__ __align__(16) __hip_bfloat16 A2[128 * 264];  // rad -> hidden -> msg (67.6KB)
  __shared__ float distb[128];
  __shared__ int srow[128], scol[128];
  __shared__ float red[8][128], redsq[8][128];
  __shared__ float mv[128][2];
  __shared__ float cb1b[128], cw2b[128];

  const int tid = threadIdx.x, w = tid >> 6, l = tid & 63, r = l & 15, g = l >> 4;
  const int e0 = blockIdx.x * 128;

  if (tid < 128) {
    cb1b[tid] = cn_b1[tid];
    cw2b[tid] = cn_w2[tid];
  }
  if (tid < 128) {
    int e = elist[e0 + tid];
    int r2 = ei[e], c2 = ei[EE + e];
    srow[tid] = r2;
    scol[tid] = c2;
    float ex = pos[c2 * 3 + 0] - pos[r2 * 3 + 0] + 1e-8f;
    float ey = pos[c2 * 3 + 1] - pos[r2 * 3 + 1] + 1e-8f;
    float ez = pos[c2 * 3 + 2] - pos[r2 * 3 + 2] + 1e-8f;
    distb[tid] = sqrtf(ex * ex + ey * ey + ez * ez);
  }
  __syncthreads();  // #1: meta ready

  // ---- rad pre-pass (transposed MFMA): wave w owns edges [w*16, w*16+16) ----
  unsigned short* A2u = (unsigned short*)A2;
  {
    const int eloc = w * 16 + r;
    float d = distb[eloc];
    bf16x8 sfrag;
#pragma unroll
    for (int j = 0; j < 8; ++j) {
      float x = d * rb_w1[g * 8 + j] + rb_b1[g * 8 + j];
      sfrag[j] = (__bf16)silu_f(x);
    }
#pragma unroll
    for (int t = 0; t < 16; ++t) {
      int cbase = t * 16 + g * 4;
      bf16x8 afr = *(const bf16x8*)(RWT + (size_t)(t * 16 + r) * 32 + g * 8);
      f32x4 rad = __builtin_amdgcn_mfma_f32_16x16x32_bf16(
          afr, sfrag, (f32x4){0.f, 0.f, 0.f, 0.f}, 0, 0, 0);
      ushort4 o;
      o.x = bf_bits(rad[0]);
      o.y = bf_bits(rad[1]);
      o.z = bf_bits(rad[2]);
      o.w = bf_bits(rad[3]);
      *(ushort4*)(A2u + (size_t)eloc * 264 + cbase) = o;
    }
  }
  __syncthreads();  // #2: rad in A2

  // ---- staging: hidden = silu(rad + P1 + P2 + b1p), coalesced 16B gathers ----
#pragma unroll
  for (int it = 0; it < 8; ++it) {
    int ch = it * 512 + tid;  // 4096 chunks of 8 elems
    int i = ch >> 5, c = ch & 31;
    bf16x8 radv = *(const bf16x8*)(A2 + i * 264 + c * 8);
    bf16x8 p1 = *(const bf16x8*)(Pb + (size_t)srow[i] * 512 + c * 8);
    bf16x8 p2 = *(const bf16x8*)(Pb + (size_t)scol[i] * 512 + 256 + c * 8);
    float4 b1a = *(const float4*)(b1p + c * 8);
    float4 b1b = *(const float4*)(b1p + c * 8 + 4);
    float bv[8] = {b1a.x, b1a.y, b1a.z, b1a.w, b1b.x, b1b.y, b1b.z, b1b.w};
    bf16x8 o;
#pragma unroll
    for (int j = 0; j < 8; ++j)
      o[j] = (__bf16)silu_f((float)radv[j] + (float)p1[j] + (float)p2[j] + bv[j]);
    *(bf16x8*)(A2 + i * 264 + c * 8) = o;
  }
  __syncthreads();  // #3: hidden ready

  // ---- GEMM2 (transposed): D[c'][e], A=W2T rows, B=A2 rows (e = nf*16+r) ----
  f32x4 acc[2][8];
#pragma unroll
  for (int a = 0; a < 2; ++a)
#pragma unroll
    for (int b = 0; b < 8; ++b) acc[a][b] = (f32x4){0.f, 0.f, 0.f, 0.f};
  for (int ks = 0; ks < 8; ++ks) {
    bf16x8 af[2], bfr[8];
#pragma unroll
    for (int mf = 0; mf < 2; ++mf)
      af[mf] = *(const bf16x8*)(W2T + (size_t)(w * 32 + mf * 16 + r) * 256 + ks * 32 + g * 8);
#pragma unroll
    for (int nf = 0; nf < 8; ++nf)
      bfr[nf] = *(const bf16x8*)(A2 + (nf * 16 + r) * 264 + ks * 32 + g * 8);
#pragma unroll
    for (int mf = 0; mf < 2; ++mf)
#pragma unroll
      for (int nf = 0; nf < 8; ++nf)
        acc[mf][nf] =
            __builtin_amdgcn_mfma_f32_16x16x32_bf16(af[mf], bfr[nf], acc[mf][nf], 0, 0, 0);
  }
  {
    float4 b2v0 = *(const float4*)(en_b2 + w * 32 + g * 4);
    float4 b2v1 = *(const float4*)(en_b2 + w * 32 + 16 + g * 4);
#pragma unroll
    for (int nf = 0; nf < 8; ++nf) {
      acc[0][nf][0] += b2v0.x;
      acc[0][nf][1] += b2v0.y;
      acc[0][nf][2] += b2v0.z;
      acc[0][nf][3] += b2v0.w;
      acc[1][nf][0] += b2v1.x;
      acc[1][nf][1] += b2v1.y;
      acc[1][nf][2] += b2v1.z;
      acc[1][nf][3] += b2v1.w;
    }
  }

  // ---- LN stats ----
#pragma unroll
  for (int nf = 0; nf < 8; ++nf) {
    float s = 0.f, sq = 0.f;
#pragma unroll
    for (int mf = 0; mf < 2; ++mf)
#pragma unroll
      for (int q = 0; q < 4; ++q) {
        float v = acc[mf][nf][q];
        s += v;
        sq += v * v;
      }
    s += __shfl_xor(s, 16, 64);
    s += __shfl_xor(s, 32, 64);
    sq += __shfl_xor(sq, 16, 64);
    sq += __shfl_xor(sq, 32, 64);
    if (l < 16) {
      red[w][nf * 16 + l] = s;
      redsq[w][nf * 16 + l] = sq;
    }
  }
  __syncthreads();  // #4
  if (tid < 128) {
    float s = 0.f, sq = 0.f;
#pragma unroll
    for (int k = 0; k < 8; ++k) {
      s += red[k][tid];
      sq += redsq[k][tid];
    }
    float mean = s * (1.0f / HH);
    float var = sq * (1.0f / HH) - mean * mean;
    mv[tid][0] = mean;
    mv[tid][1] = rsqrtf(var + 1e-5f);
  }
  __syncthreads();  // #5

  // ---- LN apply: packed ushort4 writes into A2 ----
  {
    float4 gv0 = *(const float4*)(en_g + w * 32 + g * 4);
    float4 gv1 = *(const float4*)(en_g + w * 32 + 16 + g * 4);
    float4 bv0 = *(const float4*)(en_bt + w * 32 + g * 4);
    float4 bv1 = *(const float4*)(en_bt + w * 32 + 16 + g * 4);
#pragma unroll
    for (int nf = 0; nf < 8; ++nf) {
      int e = nf * 16 + r;
      float mm = mv[e][0], rs = mv[e][1];
      ushort4 o0, o1;
      o0.x = bf_bits((acc[0][nf][0] - mm) * rs * gv0.x + bv0.x);
      o0.y = bf_bits((acc[0][nf][1] - mm) * rs * gv0.y + bv0.y);
      o0.z = bf_bits((acc[0][nf][2] - mm) * rs * gv0.z + bv0.z);
      o0.w = bf_bits((acc[0][nf][3] - mm) * rs * gv0.w + bv0.w);
      o1.x = bf_bits((acc[1][nf][0] - mm) * rs * gv1.x + bv1.x);
      o1.y = bf_bits((acc[1][nf][1] - mm) * rs * gv1.y + bv1.y);
      o1.z = bf_bits((acc[1][nf][2] - mm) * rs * gv1.z + bv1.z);
      o1.w = bf_bits((acc[1][nf][3] - mm) * rs * gv1.w + bv1.w);
      *(ushort4*)(A2u + (size_t)e * 264 + w * 32 + g * 4) = o0;
      *(ushort4*)(A2u + (size_t)e * 264 + w * 32 + 16 + g * 4) = o1;
    }
  }
  __syncthreads();  // #6: msg ready in A2

  // ---- segmented nmsg reduction (lane-contiguous; plain stores interior) ----
  {
    int c = tid & 255, h = tid >> 8;
    int rbeg = h * 64, rend = rbeg + 64;
    int segstart = rbeg;
    int cur = scol[rbeg];
    float run = 0.f;
    for (int row = rbeg; row < rend; ++row) {
      int nd = scol[row];
      if (nd != cur) {
        float* dst = &nmsg[(size_t)cur * 256 + c];
        if (segstart > rbeg)
          *dst = run;  // interior segment: exclusive by CSR contiguity
        else
          atomicAdd(dst, run);
        segstart = row;
        cur = nd;
        run = 0.f;
      }
      run += ubf(A2u[(size_t)row * 264 + c]);
    }
    atomicAdd(&nmsg[(size_t)cur * 256 + c], run);
  }

  // ---- coord head (R4 orientation): D[e][c'], af = msg rows, bf = CW1T row ----
  f32x4 c2a[8];
#pragma unroll
  for (int a = 0; a < 8; ++a) c2a[a] = (f32x4){0.f, 0.f, 0.f, 0.f};
  for (int ks = 0; ks < 8; ++ks) {
    bf16x8 bfr = *(const bf16x8*)(CW1T + (size_t)(w * 16 + r) * 256 + ks * 32 + g * 8);
#pragma unroll
    for (int fm = 0; fm < 8; ++fm) {
      bf16x8 af = *(const bf16x8*)(A2 + (fm * 16 + r) * 264 + ks * 32 + g * 8);
      c2a[fm] = __builtin_amdgcn_mfma_f32_16x16x32_bf16(af, bfr, c2a[fm], 0, 0, 0);
    }
  }
  {
    int ccol = w * 16 + r;
    float cb = cb1b[ccol], cw = cw2b[ccol];
#pragma unroll
    for (int fm = 0; fm < 8; ++fm)
#pragma unroll
      for (int q = 0; q < 4; ++q) {
        float v = silu_f(c2a[fm][q] + cb) * cw;
#pragma unroll
        for (int m = 1; m < 16; m <<= 1) v += __shfl_xor(v, m, 64);
        if (r == 0) red[w][fm * 16 + g * 4 + q] = v;
      }
  }
  __syncthreads();  // #7
  if (tid < 128) {
    float s = cn_b2[0];
#pragma unroll
    for (int k = 0; k < 8; ++k) s += red[k][tid];
    float wgt = tanhf(s);
    int rr = srow[tid], cc = scol[tid];
    float ax = pos[cc * 3 + 0] - pos[rr * 3 + 0];
    float ay = pos[cc * 3 + 1] - pos[rr * 3 + 1];
    float az = pos[cc * 3 + 2] - pos[rr * 3 + 2];
    atomicAdd(&pos_out[rr * 3 + 0], -wgt * ax);
    atomicAdd(&pos_out[rr * 3 + 1], -wgt * ay);
    atomicAdd(&pos_out[rr * 3 + 2], -wgt * az);
    atomicAdd(&pos_out[cc * 3 + 0], wgt * ax);
    atomicAdd(&pos_out[cc * 3 + 1], wgt * ay);
    atomicAdd(&pos_out[cc * 3 + 2], wgt * az);
  }
}

// ---------------- fused node kernel: 64 nodes/block, 8 waves; nmsg f32 ----------------
__global__ __launch_bounds__(512, 4) void node_kernel(
    const __hip_bfloat16* __restrict__ hb, const float* __restrict__ nmsg,
    const __hip_bfloat16* __restrict__ NW1T, const float* __restrict__ nn_b1,
    const __hip_bfloat16* __restrict__ NW2T, const float* __restrict__ nn_b2,
    const float* __restrict__ nn_g, const float* __restrict__ nn_bt,
    float* __restrict__ out_h) {
  __shared__ __align__(16) __hip_bfloat16 A2[64 * 264];
  __shared__ float red[8][64], redsq[8][64];
  __shared__ float mv[64][2];
  __shared__ float gb[HH], btb[HH];
  const int tid = threadIdx.x, w = tid >> 6, l = tid & 63, r = l & 15, g = l >> 4;
  const int n0 = blockIdx.x * 64;
  if (tid < 256) {
    gb[tid] = nn_g[tid];
    btb[tid] = nn_bt[tid];
  }

  f32x4 acc[4][2];
#pragma unroll
  for (int a = 0; a < 4; ++a)
#pragma unroll
    for (int b = 0; b < 2; ++b) acc[a][b] = (f32x4){0.f, 0.f, 0.f, 0.f};
  for (int ks = 0; ks < 8; ++ks) {
    bf16x8 af[4], bfr[2];
#pragma unroll
    for (int fm = 0; fm < 4; ++fm)
      af[fm] = *(const bf16x8*)(hb + (size_t)(n0 + fm * 16 + r) * 256 + ks * 32 + g * 8);
#pragma unroll
    for (int fn = 0; fn < 2; ++fn)
      bfr[fn] = *(const bf16x8*)(NW1T + (size_t)(w * 32 + fn * 16 + r) * 512 + ks * 32 + g * 8);
#pragma unroll
    for (int fm = 0; fm < 4; ++fm)
#pragma unroll
      for (int fn = 0; fn < 2; ++fn)
        acc[fm][fn] =
            __builtin_amdgcn_mfma_f32_16x16x32_bf16(af[fm], bfr[fn], acc[fm][fn], 0, 0, 0);
  }
  for (int ks = 0; ks < 8; ++ks) {
    bf16x8 af[4], bfr[2];
#pragma unroll
    for (int fm = 0; fm < 4; ++fm) {
      const float* src = nmsg + (size_t)(n0 + fm * 16 + r) * 256 + ks * 32 + g * 8;
      float4 a0 = *(const float4*)src;
      float4 a1 = *(const float4*)(src + 4);
      bf16x8 v;
      v[0] = (__bf16)a0.x;
      v[1] = (__bf16)a0.y;
      v[2] = (__bf16)a0.z;
      v[3] = (__bf16)a0.w;
      v[4] = (__bf16)a1.x;
      v[5] = (__bf16)a1.y;
      v[6] = (__bf16)a1.z;
      v[7] = (__bf16)a1.w;
      af[fm] = v;
    }
#pragma unroll
    for (int fn = 0; fn < 2; ++fn)
      bfr[fn] =
          *(const bf16x8*)(NW1T + (size_t)(w * 32 + fn * 16 + r) * 512 + 256 + ks * 32 + g * 8);
#pragma unroll
    for (int fm = 0; fm < 4; ++fm)
#pragma unroll
      for (int fn = 0; fn < 2; ++fn)
        acc[fm][fn] =
            __builtin_amdgcn_mfma_f32_16x16x32_bf16(af[fm], bfr[fn], acc[fm][fn], 0, 0, 0);
  }
  __syncthreads();
#pragma unroll
  for (int fn = 0; fn < 2; ++fn) {
    int col = w * 32 + fn * 16 + r;
    float b1 = nn_b1[col];
#pragma unroll
    for (int fm = 0; fm < 4; ++fm)
#pragma unroll
      for (int q = 0; q < 4; ++q) {
        int row = fm * 16 + g * 4 + q;
        A2[row * 264 + col] = __float2bfloat16(silu_f(acc[fm][fn][q] + b1));
      }
  }
  __syncthreads();

#pragma unroll
  for (int a = 0; a < 4; ++a)
#pragma unroll
    for (int b = 0; b < 2; ++b) acc[a][b] = (f32x4){0.f, 0.f, 0.f, 0.f};
  for (int ks = 0; ks < 8; ++ks) {
    bf16x8 af[4], bfr[2];
#pragma unroll
    for (int fm = 0; fm < 4; ++fm)
      af[fm] = *(const bf16x8*)(A2 + (fm * 16 + r) * 264 + ks * 32 + g * 8);
#pragma unroll
    for (int fn = 0; fn < 2; ++fn)
      bfr[fn] = *(const bf16x8*)(NW2T + (size_t)(w * 32 + fn * 16 + r) * 256 + ks * 32 + g * 8);
#pragma unroll
    for (int fm = 0; fm < 4; ++fm)
#pragma unroll
      for (int fn = 0; fn < 2; ++fn)
        acc[fm][fn] =
            __builtin_amdgcn_mfma_f32_16x16x32_bf16(af[fm], bfr[fn], acc[fm][fn], 0, 0, 0);
  }
#pragma unroll
  for (int fn = 0; fn < 2; ++fn) {
    float b2 = nn_b2[w * 32 + fn * 16 + r];
#pragma unroll
    for (int fm = 0; fm < 4; ++fm)
#pragma unroll
      for (int q = 0; q < 4; ++q) acc[fm][fn][q] += b2;
  }
#pragma unroll
  for (int fm = 0; fm < 4; ++fm)
#pragma unroll
    for (int q = 0; q < 4; ++q) {
      float s = acc[fm][0][q] + acc[fm][1][q];
      float sq = acc[fm][0][q] * acc[fm][0][q] + acc[fm][1][q] * acc[fm][1][q];
#pragma unroll
      for (int m = 1; m < 16; m <<= 1) {
        s += __shfl_xor(s, m, 64);
        sq += __shfl_xor(sq, m, 64);
      }
      if (r == 0) {
        red[w][fm * 16 + g * 4 + q] = s;
        redsq[w][fm * 16 + g * 4 + q] = sq;
      }
    }
  __syncthreads();
  if (tid < 64) {
    float s = 0.f, sq = 0.f;
#pragma unroll
    for (int k = 0; k < 8; ++k) {
      s += red[k][tid];
      sq += redsq[k][tid];
    }
    float mean = s * (1.0f / HH);
    float var = sq * (1.0f / HH) - mean * mean;
    mv[tid][0] = mean;
    mv[tid][1] = rsqrtf(var + 1e-5f);
  }
  __syncthreads();
#pragma unroll
  for (int fn = 0; fn < 2; ++fn) {
    int col = w * 32 + fn * 16 + r;
    float gg = gb[col], bb = btb[col];
#pragma unroll
    for (int fm = 0; fm < 4; ++fm)
#pragma unroll
      for (int q = 0; q < 4; ++q) {
        int row = fm * 16 + g * 4 + q;
        out_h[(size_t)(n0 + row) * HH + col] =
            (acc[fm][fn][q] - mv[row][0]) * mv[row][1] * gg + bb;
      }
  }
}

// ---------------- launch ----------------
extern "C" void kernel_launch(void* const* d_in, const int* in_sizes, int n_in,
                              void* d_out, int out_size, void* d_ws, size_t ws_size,
                              hipStream_t stream) {
  const float* h = (const float*)d_in[0];
  const float* pos = (const float*)d_in[1];
  const float* rb_w1 = (const float*)d_in[2];
  const float* rb_b1 = (const float*)d_in[3];
  const float* rb_w2 = (const float*)d_in[4];
  const float* rb_b2 = (const float*)d_in[5];
  const float* en_w1 = (const float*)d_in[6];
  const float* en_b1 = (const float*)d_in[7];
  const float* en_w2 = (const float*)d_in[8];
  const float* en_b2 = (const float*)d_in[9];
  const float* en_g = (const float*)d_in[10];
  const float* en_bt = (const float*)d_in[11];
  const float* nn_w1 = (const float*)d_in[12];
  const float* nn_b1 = (const float*)d_in[13];
  const float* nn_w2 = (const float*)d_in[14];
  const float* nn_b2 = (const float*)d_in[15];
  const float* nn_g = (const float*)d_in[16];
  const float* nn_bt = (const float*)d_in[17];
  const float* cn_w1 = (const float*)d_in[18];
  const float* cn_b1 = (const float*)d_in[19];
  const float* cn_w2 = (const float*)d_in[20];
  const float* cn_b2 = (const float*)d_in[21];
  const int* ei = (const int*)d_in[22];

  float* out_h = (float*)d_out;
  float* out_pos = out_h + (size_t)NN * HH;

  char* p = (char*)d_ws;
  auto alloc = [&p](size_t bytes) {
    char* q = p;
    p += (bytes + 255) & ~(size_t)255;
    return q;
  };
  __hip_bfloat16* hb = (__hip_bfloat16*)alloc((size_t)NN * HH * 2);
  __hip_bfloat16* Pb = (__hip_bfloat16*)alloc((size_t)NN * 512 * 2);
  __hip_bfloat16* W1abT = (__hip_bfloat16*)alloc((size_t)512 * 256 * 2);
  __hip_bfloat16* W2T = (__hip_bfloat16*)alloc((size_t)256 * 256 * 2);
  __hip_bfloat16* NW1T = (__hip_bfloat16*)alloc((size_t)256 * 512 * 2);
  __hip_bfloat16* NW2T = (__hip_bfloat16*)alloc((size_t)256 * 256 * 2);
  __hip_bfloat16* CW1T = (__hip_bfloat16*)alloc((size_t)128 * 256 * 2);
  __hip_bfloat16* RWT = (__hip_bfloat16*)alloc((size_t)256 * 32 * 2);
  float* b1p = (float*)alloc((size_t)256 * 4);
  float* nmsg = (float*)alloc((size_t)NN * HH * 4);
  int* counts = (int*)alloc((size_t)NN * 4);
  int* offs = (int*)alloc((size_t)(NN + 1) * 4);
  int* cursor = (int*)alloc((size_t)NN * 4);
  int* elist = (int*)alloc((size_t)EE * 4);
  int* bsum = (int*)alloc((size_t)64 * 4);
  int* bbase = (int*)alloc((size_t)64 * 4);

  hipMemsetAsync(out_pos, 0, (size_t)NN * 3 * sizeof(float), stream);
  hipMemsetAsync(counts, 0, (size_t)NN * sizeof(int), stream);
  hipMemsetAsync(nmsg, 0, (size_t)NN * HH * sizeof(float), stream);

  prep_all_kernel<<<6817, 256, 0, stream>>>(h, ei, en_w1, en_w2, nn_w1, nn_w2, cn_w1, rb_w2,
                                            rb_b2, en_b1, hb, W2T, NW1T, NW2T, CW1T, W1abT,
                                            RWT, b1p, counts);
  scanA_kernel<<<NN / 256, 256, 0, stream>>>(counts, bsum);
  scanB_kernel<<<1, 64, 0, stream>>>(bsum, bbase, offs);
  scanC_kernel<<<NN / 256, 256, 0, stream>>>(counts, bbase, offs, cursor);
  scatter_kernel<<<EE / 256, 256, 0, stream>>>(ei, cursor, elist);
  pgemm_kernel<<<NN / 64, 512, 0, stream>>>(hb, W1abT, Pb);
  edge_kernel<<<EE / 128, 512, 0, stream>>>(Pb, ei, pos, rb_w1, rb_b1, RWT, b1p, W2T, en_b2,
                                            en_g, en_bt, CW1T, cn_b1, cn_w2, cn_b2, elist,
                                            nmsg, out_pos);
  node_kernel<<<NN / 64, 512, 0, stream>>>(hb, nmsg, NW1T, nn_b1, NW2T, nn_b2, nn_g, nn_bt,
                                           out_h);
}